// Round 14
// baseline (218.551 us; speedup 1.0000x reference)
//
#include <hip/hip_runtime.h>

#define NN     50000
#define E_RAW  800000
#define ETOT   (E_RAW + NN)   /* 850000: edges + self loops */
#define FIN    128
#define FH     256            /* HEADS*HID */
#define NEG    0.2f
#define BCAP   64             /* bucket capacity; P(deg>64) ~ 1e-18 */

/* Counting-sort CSR build (R13/R14).  R9: global atomics cap ~11 ops/ns ->
   LDS histograms.  R14: scatter WGs compute their own cursors from pcnt
   (no offset pass, no soff) and ride in the gemm dispatch (256-thr blocks,
   LDS unioned) so scatter overlaps MFMA work. */
#define P_PART 16
#define DPW    3125             /* dsts per partition, 12.5KB LDS */
#define R_REP  16
#define EPW    (E_RAW / R_REP)  /* 50000 edges per replica */
#define CNT_WGS (P_PART * R_REP) /* 256 count WGs (1024 thr) */
#define PREP_WGS 8              /* W1 transpose: 8 x 4096 elems */
#define SC2_NB  (P_PART * R_REP) /* 256 scatter WGs (256 thr) */
#define GEMM_NB ((NN + 63) / 64) /* 782 gemm blocks */

typedef __attribute__((ext_vector_type(8))) short s16x8;
typedef __attribute__((ext_vector_type(4))) float f32x4;

static __device__ __forceinline__ float leaky(float v) { return v > 0.f ? v : NEG * v; }

// RNE float->bf16
static __device__ __forceinline__ unsigned short f2bf(float f) {
    unsigned u = __float_as_uint(f);
    unsigned r = u + 0x7fffu + ((u >> 16) & 1u);
    return (unsigned short)(r >> 16);
}

// ---------------------------------------------------------------------------
// D1: count pass + W1 prep.
// blocks [0,256): WG(p=b>>4, r=b&15) histograms dst stream slice r into LDS
//   (non-returning ds_add), writes pcnt[r*NN + d] coalesced.
// blocks [256,264): W1 fp32 [k][col] -> bf16 Wt_bf[col][k] (strided).
// ---------------------------------------------------------------------------
__global__ __launch_bounds__(1024) void k_count(const int* __restrict__ ei,
                                                const float* __restrict__ W1,
                                                unsigned short* __restrict__ Wt_bf,
                                                int* __restrict__ pcnt)
{
    const int t = threadIdx.x;
    if (blockIdx.x >= CNT_WGS) {
        const int base = (blockIdx.x - CNT_WGS) * 4096;
        for (int i = t; i < 4096; i += 1024) {
            int idx = base + i;                 // < 32768
            int k = idx >> 8, col = idx & 255;
            Wt_bf[col * FIN + k] = f2bf(W1[k * FH + col]);
        }
        return;
    }
    __shared__ int lcnt[DPW];
    const int p  = blockIdx.x >> 4;
    const int r  = blockIdx.x & 15;
    const int lo = p * DPW;
    for (int i = t; i < DPW; i += 1024) lcnt[i] = 0;
    __syncthreads();
    const int ebase = r * EPW, eend = ebase + EPW;
    for (int e0 = ebase + t * 4; e0 < eend; e0 += 4096) {
        int4 dv4 = *(const int4*)&ei[E_RAW + e0];   // coalesced 16B
#pragma unroll
        for (int k = 0; k < 4; k++) {
            unsigned rel = (unsigned)((&dv4.x)[k] - lo);
            if (rel < DPW) atomicAdd(&lcnt[rel], 1);   // LDS, no return
        }
    }
    __syncthreads();
    for (int i = t; i < DPW; i += 1024)
        pcnt[r * NN + lo + i] = lcnt[i];
}

// ---------------------------------------------------------------------------
// D2: FUSED scatter + gemm (256-thread blocks; 32KB LDS union).
// blocks [0,256): scat WG(p=b>>4, r=b&15): cursors computed inline from pcnt
//   (run = 1 + sum_{r'<r}); r==15 writes cnt; r==0 seeds self-loop slot 0;
//   then scans edge slice r (src+dst int4), ds_add_rtn + store into the
//   contiguous bucket csr_src[d*64 + pos].
// blocks [256, 256+782): h1 = x@W1 via MFMA bf16 (R7 path).
// ---------------------------------------------------------------------------
__global__ __launch_bounds__(256) void k_gx(const float* __restrict__ x,
                                            const unsigned short* __restrict__ Wt_bf,
                                            const float* __restrict__ att_src,
                                            const float* __restrict__ att_dst,
                                            const int* __restrict__ ei,
                                            const int* __restrict__ pcnt,
                                            int* __restrict__ cnt,
                                            int* __restrict__ csr_src,
                                            unsigned short* __restrict__ h1b,
                                            float* __restrict__ a_s,
                                            float* __restrict__ a_d)
{
    __shared__ __align__(16) unsigned char SbufRaw[64 * 256 * 2];  // 32 KB union
    const int t = threadIdx.x;

    // ---------------- scatter path ----------------
    if (blockIdx.x < SC2_NB) {
        int* cur = (int*)SbufRaw;                 // 12.5 KB of the union
        const int p  = blockIdx.x >> 4;
        const int r  = blockIdx.x & 15;
        const int lo = p * DPW;
        for (int i = t; i < DPW; i += 256) {
            int run = 1, tot = 1;                 // slot 0 = self loop
#pragma unroll
            for (int rr = 0; rr < R_REP; rr++) {
                int v = pcnt[rr * NN + lo + i];
                if (rr < r) run += v;
                tot += v;
            }
            cur[i] = run;
            if (r == 15) cnt[lo + i] = tot;
            if (r == 0)  csr_src[(size_t)(lo + i) << 6] = lo + i;  // self-loop
        }
        __syncthreads();
        const int ebase = r * EPW, eend = ebase + EPW;
        for (int e0 = ebase + t * 4; e0 < eend; e0 += 1024) {
            int4 sv4 = *(const int4*)&ei[e0];           // coalesced 16B (src)
            int4 dv4 = *(const int4*)&ei[E_RAW + e0];   // coalesced 16B (dst)
#pragma unroll
            for (int k = 0; k < 4; k++) {
                int d = (&dv4.x)[k];
                unsigned rel = (unsigned)(d - lo);
                if (rel < DPW) {
                    int pos = atomicAdd(&cur[rel], 1);  // LDS ds_add_rtn
                    if (pos < BCAP)
                        csr_src[((size_t)d << 6) + pos] = (&sv4.x)[k];
                }
            }
        }
        return;
    }

    // ---------------- gemm path ----------------
    unsigned short* Sbuf = (unsigned short*)SbufRaw;
    const int w    = t >> 6;
    const int lane = t & 63;
    const int li   = lane & 15;
    const int q8   = (lane >> 4) * 8;
    const int quad = lane >> 4;
    const int n0   = (blockIdx.x - SC2_NB) * 64;

    {
        const int node_l = t >> 2;
        const int k0 = (t & 3) * 32;
        int nn = n0 + node_l; if (nn >= NN) nn = NN - 1;
        const float* xp = &x[(size_t)nn * FIN + k0];
        unsigned short* xd = &Sbuf[node_l * 136 + k0];
#pragma unroll
        for (int i = 0; i < 8; i++) {
            float4 v = *(const float4*)&xp[i * 4];
            xd[i * 4 + 0] = f2bf(v.x);
            xd[i * 4 + 1] = f2bf(v.y);
            xd[i * 4 + 2] = f2bf(v.z);
            xd[i * 4 + 3] = f2bf(v.w);
        }
    }
    __syncthreads();

    f32x4 acc[4][4];
#pragma unroll
    for (int i = 0; i < 4; i++)
#pragma unroll
        for (int j = 0; j < 4; j++) acc[i][j] = (f32x4){0.f, 0.f, 0.f, 0.f};

#pragma unroll
    for (int kki = 0; kki < 4; kki++) {
        const int kk = kki * 32;
        s16x8 af[4], bf[4];
#pragma unroll
        for (int n16 = 0; n16 < 4; n16++) {
            int col = w * 64 + n16 * 16 + li;
            bf[n16] = *(const s16x8*)&Wt_bf[col * FIN + kk + q8];
        }
#pragma unroll
        for (int m16 = 0; m16 < 4; m16++)
            af[m16] = *(const s16x8*)&Sbuf[(m16 * 16 + li) * 136 + kk + q8];
#pragma unroll
        for (int m16 = 0; m16 < 4; m16++)
#pragma unroll
            for (int n16 = 0; n16 < 4; n16++)
                acc[m16][n16] = __builtin_amdgcn_mfma_f32_16x16x32_bf16(
                    af[m16], bf[n16], acc[m16][n16], 0, 0, 0);
    }

    // epilogue A: per-head attention logits
    {
        float as_c[4], ad_c[4];
#pragma unroll
        for (int n16 = 0; n16 < 4; n16++) {
            int col = w * 64 + n16 * 16 + li;
            as_c[n16] = att_src[col];
            ad_c[n16] = att_dst[col];
        }
#pragma unroll
        for (int m16 = 0; m16 < 4; m16++) {
            float ps[4], pd[4];
#pragma unroll
            for (int reg = 0; reg < 4; reg++) {
                float s = 0.f, d = 0.f;
#pragma unroll
                for (int n16 = 0; n16 < 4; n16++) {
                    s += acc[m16][n16][reg] * as_c[n16];
                    d += acc[m16][n16][reg] * ad_c[n16];
                }
                ps[reg] = s; pd[reg] = d;
            }
#pragma unroll
            for (int off = 1; off < 16; off <<= 1) {
#pragma unroll
                for (int reg = 0; reg < 4; reg++) {
                    ps[reg] += __shfl_xor(ps[reg], off);
                    pd[reg] += __shfl_xor(pd[reg], off);
                }
            }
            if (li == 0) {
#pragma unroll
                for (int reg = 0; reg < 4; reg++) {
                    int node = n0 + m16 * 16 + quad * 4 + reg;
                    if (node < NN) {
                        a_s[node * 4 + w] = ps[reg];
                        a_d[node * 4 + w] = pd[reg];
                    }
                }
            }
        }
    }

    // epilogue B: bf16 store via LDS round-trip
    __syncthreads();
#pragma unroll
    for (int m16 = 0; m16 < 4; m16++)
#pragma unroll
        for (int n16 = 0; n16 < 4; n16++)
#pragma unroll
            for (int reg = 0; reg < 4; reg++)
                Sbuf[(m16 * 16 + quad * 4 + reg) * FH + w * 64 + n16 * 16 + li] =
                    f2bf(acc[m16][n16][reg]);
    __syncthreads();
    {
        const int node_l = t >> 2;
        const int c0 = (t & 3) * 64;
        int node = n0 + node_l;
        if (node < NN) {
#pragma unroll
            for (int i = 0; i < 8; i++)
                *(uint4*)&h1b[(size_t)node * FH + c0 + i * 8] =
                    *(const uint4*)&Sbuf[node_l * FH + c0 + i * 8];
        }
    }
}

// ---------------------------------------------------------------------------
// D3: layer-1 aggregation (contiguous bucket).  ONE wave per dst; lane l
// owns channels 4l..4l+3.  8B h1b gather + per-lane a_s1 + in-loop exp.
// FUSED: /z, +b1, ELU, W2 projection, layer-2 logits -> nd4.
// At its structural rate: 207MB fabric @ ~3 TB/s + VALUBusy ~67% (R13).
// ---------------------------------------------------------------------------
__global__ __launch_bounds__(256) void k_agg1(const int* __restrict__ cnt,
                                              const int* __restrict__ csr_src,
                                              const float* __restrict__ a_s1,
                                              const float* __restrict__ a_d1,
                                              const unsigned short* __restrict__ h1b,
                                              const float* __restrict__ b1,
                                              const float* __restrict__ W2,
                                              const float* __restrict__ att_src2,
                                              const float* __restrict__ att_dst2,
                                              float4* __restrict__ nd4)
{
    const int lane = threadIdx.x & 63;
    const int n = blockIdx.x * 4 + (threadIdx.x >> 6);
    if (n >= NN) return;
    int m = cnt[n]; if (m > BCAP) m = BCAP;
    const int h = lane >> 4;
    const float ad_h = a_d1[n * 4 + h];
    float acc0 = 0.f, acc1 = 0.f, acc2 = 0.f, acc3 = 0.f, z = 0.f;
    const int* sp = &csr_src[(size_t)n << 6];
#pragma unroll 4
    for (int j = 0; j < m; j++) {
        int s = sp[j];                           // wave-uniform 4B
        float as_h = a_s1[s * 4 + h];
        float ex = __expf(leaky(as_h + ad_h));
        unsigned long long wv =
            *(const unsigned long long*)(h1b + (size_t)s * FH + lane * 4);
        unsigned lo = (unsigned)wv, hi = (unsigned)(wv >> 32);
        acc0 += __uint_as_float(lo << 16) * ex;
        acc1 += __uint_as_float(lo & 0xffff0000u) * ex;
        acc2 += __uint_as_float(hi << 16) * ex;
        acc3 += __uint_as_float(hi & 0xffff0000u) * ex;
        z += ex;
    }
    const int c0 = lane * 4;
    float4 bb = *(const float4*)&b1[c0];
    float v0 = acc0 / z + bb.x;
    float v1 = acc1 / z + bb.y;
    float v2 = acc2 / z + bb.z;
    float v3 = acc3 / z + bb.w;
    v0 = v0 > 0.f ? v0 : __expf(v0) - 1.f;   // ELU
    v1 = v1 > 0.f ? v1 : __expf(v1) - 1.f;
    v2 = v2 > 0.f ? v2 : __expf(v2) - 1.f;
    v3 = v3 > 0.f ? v3 : __expf(v3) - 1.f;
    float4 w2a = *(const float4*)&W2[c0 * 2];
    float4 w2b = *(const float4*)&W2[c0 * 2 + 4];
    float s0 = v0 * w2a.x + v1 * w2a.z + v2 * w2b.x + v3 * w2b.z;
    float s1 = v0 * w2a.y + v1 * w2a.w + v2 * w2b.y + v3 * w2b.w;
#pragma unroll
    for (int off = 32; off; off >>= 1) {
        s0 += __shfl_xor(s0, off);
        s1 += __shfl_xor(s1, off);
    }
    if (lane == 0) {
        float4 nd;
        nd.x = s0; nd.y = s1;
        nd.z = s0 * att_src2[0] + s1 * att_src2[1];
        nd.w = s0 * att_dst2[0] + s1 * att_dst2[1];
        nd4[n] = nd;
    }
}

// ---------------------------------------------------------------------------
// D4: layer-2 aggregation, 16 lanes per dst, contiguous bucket; writes d_out.
// ---------------------------------------------------------------------------
__global__ __launch_bounds__(256) void k_agg2(const int* __restrict__ cnt,
                                              const int* __restrict__ csr_src,
                                              const float4* __restrict__ nd4,
                                              const float* __restrict__ b2,
                                              float* __restrict__ out)
{
    const int l = threadIdx.x & 15;
    const int n = blockIdx.x * 16 + (threadIdx.x >> 4);
    if (n >= NN) return;
    int m = cnt[n]; if (m > BCAP) m = BCAP;
    const int* sp = &csr_src[(size_t)n << 6];
    const float ad = nd4[n].w;
    float z = 0.f, a0 = 0.f, a1 = 0.f;
    for (int j = l; j < m; j += 16) {
        int s = sp[j];
        float4 f = nd4[s];
        float ex = __expf(leaky(f.z + ad));
        z  += ex;
        a0 += f.x * ex;
        a1 += f.y * ex;
    }
#pragma unroll
    for (int off = 8; off; off >>= 1) {
        z  += __shfl_xor(z, off);
        a0 += __shfl_xor(a0, off);
        a1 += __shfl_xor(a1, off);
    }
    if (l == 0) {
        out[n * 2 + 0] = a0 / z + b2[0];
        out[n * 2 + 1] = a1 / z + b2[1];
    }
}

extern "C" void kernel_launch(void* const* d_in, const int* in_sizes, int n_in,
                              void* d_out, int out_size, void* d_ws, size_t ws_size,
                              hipStream_t stream)
{
    const float* x        = (const float*)d_in[0];
    const int*   ei       = (const int*)d_in[1];
    const float* W1       = (const float*)d_in[2];
    const float* att_src1 = (const float*)d_in[3];
    const float* att_dst1 = (const float*)d_in[4];
    const float* b1       = (const float*)d_in[5];
    const float* W2       = (const float*)d_in[6];
    const float* att_src2 = (const float*)d_in[7];
    const float* att_dst2 = (const float*)d_in[8];
    const float* b2       = (const float*)d_in[9];
    float* out = (float*)d_out;

    // --- workspace layout (all regions 16B aligned) ---
    int*    csr_src = (int*)d_ws;                            // NN*64*4 = 12.8 MB
    unsigned short* h1b = (unsigned short*)(csr_src + (size_t)NN * 64); // 25.6 MB
    unsigned short* Wt_bf = h1b + (size_t)NN * FH;           // 64 KB
    int*    pcnt  = (int*)(Wt_bf + FH * FIN);                // NN*16 = 3.2 MB
    int*    cnt   = pcnt + (size_t)NN * R_REP;               // 200 KB
    float*  a_s1  = (float*)(cnt + NN);                      // 800 KB
    float*  a_d1  = a_s1 + (size_t)NN * 4;                   // 800 KB
    float4* nd4   = (float4*)(a_d1 + (size_t)NN * 4);        // 800 KB

    k_count<<<CNT_WGS + PREP_WGS, 1024, 0, stream>>>(ei, W1, Wt_bf, pcnt);
    k_gx<<<SC2_NB + GEMM_NB, 256, 0, stream>>>(x, Wt_bf, att_src1, att_dst1, ei,
                                               pcnt, cnt, csr_src, h1b, a_s1, a_d1);
    k_agg1<<<(NN + 3) / 4, 256, 0, stream>>>(cnt, csr_src, a_s1, a_d1, h1b,
                                             b1, W2, att_src2, att_dst2, nd4);
    k_agg2<<<(NN + 15) / 16, 256, 0, stream>>>(cnt, csr_src, nd4, b2, out);
}

// Round 15
// 205.643 us; speedup vs baseline: 1.0628x; 1.0628x over previous
//
#include <hip/hip_runtime.h>

#define NN     50000
#define E_RAW  800000
#define ETOT   (E_RAW + NN)   /* 850000: edges + self loops */
#define FIN    128
#define FH     256            /* HEADS*HID */
#define NEG    0.2f
#define BCAP   64             /* bucket capacity; P(deg>64) ~ 1e-18 */

/* Counting-sort CSR build.  R9: global atomics cap ~11 ops/ns -> LDS
   histograms.  R14 lesson: scatter needs its own 1024-thr dispatch (256-thr
   fused version was 5x slower).  R15: P_PART 16->8 halves the redundant
   edge-stream scanning (each WG scans 25k edges for 6.25k hits). */
#define P_PART 8
#define DPW    6250             /* dsts per partition, 25KB LDS */
#define R_REP  32
#define EPW    (E_RAW / R_REP)  /* 25000 edges per replica */
#define CNT_WGS (P_PART * R_REP) /* 256 */
#define PREP_WGS 8              /* W1 transpose: 8 x 4096 elems */
#define OFF_NB  ((NN + 255) / 256)   /* 196 offset blocks */
#define GEMM_NB ((NN + 63) / 64)     /* 782 gemm blocks */

typedef __attribute__((ext_vector_type(8))) short s16x8;
typedef __attribute__((ext_vector_type(4))) float f32x4;

static __device__ __forceinline__ float leaky(float v) { return v > 0.f ? v : NEG * v; }

// RNE float->bf16
static __device__ __forceinline__ unsigned short f2bf(float f) {
    unsigned u = __float_as_uint(f);
    unsigned r = u + 0x7fffu + ((u >> 16) & 1u);
    return (unsigned short)(r >> 16);
}

// ---------------------------------------------------------------------------
// D1: count pass + W1 prep.
// blocks [0,256): WG(p=b>>5, r=b&31) histograms dst stream slice r into LDS
//   (non-returning ds_add), writes pcnt[r*NN + d] coalesced.
// blocks [256,264): W1 fp32 [k][col] -> bf16 Wt_bf[col][k] (strided).
// ---------------------------------------------------------------------------
__global__ __launch_bounds__(1024) void k_count(const int* __restrict__ ei,
                                                const float* __restrict__ W1,
                                                unsigned short* __restrict__ Wt_bf,
                                                int* __restrict__ pcnt)
{
    const int t = threadIdx.x;
    if (blockIdx.x >= CNT_WGS) {
        const int base = (blockIdx.x - CNT_WGS) * 4096;
        for (int i = t; i < 4096; i += 1024) {
            int idx = base + i;                 // < 32768
            int k = idx >> 8, col = idx & 255;
            Wt_bf[col * FIN + k] = f2bf(W1[k * FH + col]);
        }
        return;
    }
    __shared__ int lcnt[DPW];
    const int p  = blockIdx.x >> 5;
    const int r  = blockIdx.x & 31;
    const int lo = p * DPW;
    for (int i = t; i < DPW; i += 1024) lcnt[i] = 0;
    __syncthreads();
    const int ebase = r * EPW, eend = ebase + EPW;
    for (int e0 = ebase + t * 4; e0 < eend; e0 += 4096) {
        int4 dv4 = *(const int4*)&ei[E_RAW + e0];   // coalesced 16B
#pragma unroll
        for (int k = 0; k < 4; k++) {
            unsigned rel = (unsigned)((&dv4.x)[k] - lo);
            if (rel < DPW) atomicAdd(&lcnt[rel], 1);   // LDS, no return
        }
    }
    __syncthreads();
    for (int i = t; i < DPW; i += 1024)
        pcnt[r * NN + lo + i] = lcnt[i];
}

// ---------------------------------------------------------------------------
// D2: FUSED offsets + gemm.
// blocks [0,196): per-dst prefix over 32 partial counts -> soff[r*NN+d];
//   slot 0 reserved for self-loop (csr_src[d*64]=d); cnt[d]=1+sum.
// blocks [196,978): h1 = x@W1 via MFMA bf16.
// ---------------------------------------------------------------------------
__global__ __launch_bounds__(256) void k_gx(const float* __restrict__ x,
                                            const unsigned short* __restrict__ Wt_bf,
                                            const float* __restrict__ att_src,
                                            const float* __restrict__ att_dst,
                                            const int* __restrict__ pcnt,
                                            int* __restrict__ soff,
                                            int* __restrict__ cnt,
                                            int* __restrict__ csr_src,
                                            unsigned short* __restrict__ h1b,
                                            float* __restrict__ a_s,
                                            float* __restrict__ a_d)
{
    const int t = threadIdx.x;
    if (blockIdx.x < OFF_NB) {
        int d = blockIdx.x * 256 + t;
        if (d >= NN) return;
        int run = 1;                     // slot 0 = self loop
#pragma unroll
        for (int r = 0; r < R_REP; r++) {
            soff[r * NN + d] = run;
            run += pcnt[r * NN + d];
        }
        cnt[d] = run;                    // clamped at use
        csr_src[(size_t)d << 6] = d;     // self-loop src
        return;
    }

    // ---------------- gemm path ----------------
    __shared__ unsigned short Sbuf[64 * 256];
    const int w    = t >> 6;
    const int lane = t & 63;
    const int li   = lane & 15;
    const int q8   = (lane >> 4) * 8;
    const int quad = lane >> 4;
    const int n0   = (blockIdx.x - OFF_NB) * 64;

    {
        const int node_l = t >> 2;
        const int k0 = (t & 3) * 32;
        int nn = n0 + node_l; if (nn >= NN) nn = NN - 1;
        const float* xp = &x[(size_t)nn * FIN + k0];
        unsigned short* xd = &Sbuf[node_l * 136 + k0];
#pragma unroll
        for (int i = 0; i < 8; i++) {
            float4 v = *(const float4*)&xp[i * 4];
            xd[i * 4 + 0] = f2bf(v.x);
            xd[i * 4 + 1] = f2bf(v.y);
            xd[i * 4 + 2] = f2bf(v.z);
            xd[i * 4 + 3] = f2bf(v.w);
        }
    }
    __syncthreads();

    f32x4 acc[4][4];
#pragma unroll
    for (int i = 0; i < 4; i++)
#pragma unroll
        for (int j = 0; j < 4; j++) acc[i][j] = (f32x4){0.f, 0.f, 0.f, 0.f};

#pragma unroll
    for (int kki = 0; kki < 4; kki++) {
        const int kk = kki * 32;
        s16x8 af[4], bf[4];
#pragma unroll
        for (int n16 = 0; n16 < 4; n16++) {
            int col = w * 64 + n16 * 16 + li;
            bf[n16] = *(const s16x8*)&Wt_bf[col * FIN + kk + q8];
        }
#pragma unroll
        for (int m16 = 0; m16 < 4; m16++)
            af[m16] = *(const s16x8*)&Sbuf[(m16 * 16 + li) * 136 + kk + q8];
#pragma unroll
        for (int m16 = 0; m16 < 4; m16++)
#pragma unroll
            for (int n16 = 0; n16 < 4; n16++)
                acc[m16][n16] = __builtin_amdgcn_mfma_f32_16x16x32_bf16(
                    af[m16], bf[n16], acc[m16][n16], 0, 0, 0);
    }

    // epilogue A: per-head attention logits
    {
        float as_c[4], ad_c[4];
#pragma unroll
        for (int n16 = 0; n16 < 4; n16++) {
            int col = w * 64 + n16 * 16 + li;
            as_c[n16] = att_src[col];
            ad_c[n16] = att_dst[col];
        }
#pragma unroll
        for (int m16 = 0; m16 < 4; m16++) {
            float ps[4], pd[4];
#pragma unroll
            for (int reg = 0; reg < 4; reg++) {
                float s = 0.f, d = 0.f;
#pragma unroll
                for (int n16 = 0; n16 < 4; n16++) {
                    s += acc[m16][n16][reg] * as_c[n16];
                    d += acc[m16][n16][reg] * ad_c[n16];
                }
                ps[reg] = s; pd[reg] = d;
            }
#pragma unroll
            for (int off = 1; off < 16; off <<= 1) {
#pragma unroll
                for (int reg = 0; reg < 4; reg++) {
                    ps[reg] += __shfl_xor(ps[reg], off);
                    pd[reg] += __shfl_xor(pd[reg], off);
                }
            }
            if (li == 0) {
#pragma unroll
                for (int reg = 0; reg < 4; reg++) {
                    int node = n0 + m16 * 16 + quad * 4 + reg;
                    if (node < NN) {
                        a_s[node * 4 + w] = ps[reg];
                        a_d[node * 4 + w] = pd[reg];
                    }
                }
            }
        }
    }

    // epilogue B: bf16 store via LDS round-trip
    __syncthreads();
#pragma unroll
    for (int m16 = 0; m16 < 4; m16++)
#pragma unroll
        for (int n16 = 0; n16 < 4; n16++)
#pragma unroll
            for (int reg = 0; reg < 4; reg++)
                Sbuf[(m16 * 16 + quad * 4 + reg) * FH + w * 64 + n16 * 16 + li] =
                    f2bf(acc[m16][n16][reg]);
    __syncthreads();
    {
        const int node_l = t >> 2;
        const int c0 = (t & 3) * 64;
        int node = n0 + node_l;
        if (node < NN) {
#pragma unroll
            for (int i = 0; i < 8; i++)
                *(uint4*)&h1b[(size_t)node * FH + c0 + i * 8] =
                    *(const uint4*)&Sbuf[node_l * FH + c0 + i * 8];
        }
    }
}

// ---------------------------------------------------------------------------
// D3: scatter into contiguous buckets.  WG(p,r): LDS cursors preloaded from
// soff (own slice only, coalesced), rescan (src,dst) as int4, ds_add_rtn +
// fire-and-forget store.  1024-thread WGs (R14 lesson: do NOT shrink).
// ---------------------------------------------------------------------------
__global__ __launch_bounds__(1024) void k_scat2(const int* __restrict__ ei,
                                                const int* __restrict__ soff,
                                                int* __restrict__ csr_src)
{
    __shared__ int cur[DPW];
    const int t  = threadIdx.x;
    const int p  = blockIdx.x >> 5;
    const int r  = blockIdx.x & 31;
    const int lo = p * DPW;
    for (int i = t; i < DPW; i += 1024)
        cur[i] = soff[r * NN + lo + i];
    __syncthreads();
    const int ebase = r * EPW, eend = ebase + EPW;
    for (int e0 = ebase + t * 4; e0 < eend; e0 += 4096) {
        int4 sv4 = *(const int4*)&ei[e0];           // coalesced 16B (src)
        int4 dv4 = *(const int4*)&ei[E_RAW + e0];   // coalesced 16B (dst)
#pragma unroll
        for (int k = 0; k < 4; k++) {
            int d = (&dv4.x)[k];
            unsigned rel = (unsigned)(d - lo);
            if (rel < DPW) {
                int pos = atomicAdd(&cur[rel], 1);  // LDS ds_add_rtn
                if (pos < BCAP)
                    csr_src[((size_t)d << 6) + pos] = (&sv4.x)[k];
            }
        }
    }
}

// ---------------------------------------------------------------------------
// D4: layer-1 aggregation (contiguous bucket).  ONE wave per dst; lane l
// owns channels 4l..4l+3.  8B h1b gather + per-lane a_s1 + in-loop exp.
// FUSED: /z, +b1, ELU, W2 projection, layer-2 logits -> nd4.
// At its structural rate: 207MB fabric @ ~3 TB/s + VALUBusy ~67% (R13).
// ---------------------------------------------------------------------------
__global__ __launch_bounds__(256) void k_agg1(const int* __restrict__ cnt,
                                              const int* __restrict__ csr_src,
                                              const float* __restrict__ a_s1,
                                              const float* __restrict__ a_d1,
                                              const unsigned short* __restrict__ h1b,
                                              const float* __restrict__ b1,
                                              const float* __restrict__ W2,
                                              const float* __restrict__ att_src2,
                                              const float* __restrict__ att_dst2,
                                              float4* __restrict__ nd4)
{
    const int lane = threadIdx.x & 63;
    const int n = blockIdx.x * 4 + (threadIdx.x >> 6);
    if (n >= NN) return;
    int m = cnt[n]; if (m > BCAP) m = BCAP;
    const int h = lane >> 4;
    const float ad_h = a_d1[n * 4 + h];
    float acc0 = 0.f, acc1 = 0.f, acc2 = 0.f, acc3 = 0.f, z = 0.f;
    const int* sp = &csr_src[(size_t)n << 6];
#pragma unroll 4
    for (int j = 0; j < m; j++) {
        int s = sp[j];                           // wave-uniform 4B
        float as_h = a_s1[s * 4 + h];
        float ex = __expf(leaky(as_h + ad_h));
        unsigned long long wv =
            *(const unsigned long long*)(h1b + (size_t)s * FH + lane * 4);
        unsigned lo = (unsigned)wv, hi = (unsigned)(wv >> 32);
        acc0 += __uint_as_float(lo << 16) * ex;
        acc1 += __uint_as_float(lo & 0xffff0000u) * ex;
        acc2 += __uint_as_float(hi << 16) * ex;
        acc3 += __uint_as_float(hi & 0xffff0000u) * ex;
        z += ex;
    }
    const int c0 = lane * 4;
    float4 bb = *(const float4*)&b1[c0];
    float v0 = acc0 / z + bb.x;
    float v1 = acc1 / z + bb.y;
    float v2 = acc2 / z + bb.z;
    float v3 = acc3 / z + bb.w;
    v0 = v0 > 0.f ? v0 : __expf(v0) - 1.f;   // ELU
    v1 = v1 > 0.f ? v1 : __expf(v1) - 1.f;
    v2 = v2 > 0.f ? v2 : __expf(v2) - 1.f;
    v3 = v3 > 0.f ? v3 : __expf(v3) - 1.f;
    float4 w2a = *(const float4*)&W2[c0 * 2];
    float4 w2b = *(const float4*)&W2[c0 * 2 + 4];
    float s0 = v0 * w2a.x + v1 * w2a.z + v2 * w2b.x + v3 * w2b.z;
    float s1 = v0 * w2a.y + v1 * w2a.w + v2 * w2b.y + v3 * w2b.w;
#pragma unroll
    for (int off = 32; off; off >>= 1) {
        s0 += __shfl_xor(s0, off);
        s1 += __shfl_xor(s1, off);
    }
    if (lane == 0) {
        float4 nd;
        nd.x = s0; nd.y = s1;
        nd.z = s0 * att_src2[0] + s1 * att_src2[1];
        nd.w = s0 * att_dst2[0] + s1 * att_dst2[1];
        nd4[n] = nd;
    }
}

// ---------------------------------------------------------------------------
// D5: layer-2 aggregation, 16 lanes per dst, contiguous bucket; writes d_out.
// ---------------------------------------------------------------------------
__global__ __launch_bounds__(256) void k_agg2(const int* __restrict__ cnt,
                                              const int* __restrict__ csr_src,
                                              const float4* __restrict__ nd4,
                                              const float* __restrict__ b2,
                                              float* __restrict__ out)
{
    const int l = threadIdx.x & 15;
    const int n = blockIdx.x * 16 + (threadIdx.x >> 4);
    if (n >= NN) return;
    int m = cnt[n]; if (m > BCAP) m = BCAP;
    const int* sp = &csr_src[(size_t)n << 6];
    const float ad = nd4[n].w;
    float z = 0.f, a0 = 0.f, a1 = 0.f;
    for (int j = l; j < m; j += 16) {
        int s = sp[j];
        float4 f = nd4[s];
        float ex = __expf(leaky(f.z + ad));
        z  += ex;
        a0 += f.x * ex;
        a1 += f.y * ex;
    }
#pragma unroll
    for (int off = 8; off; off >>= 1) {
        z  += __shfl_xor(z, off);
        a0 += __shfl_xor(a0, off);
        a1 += __shfl_xor(a1, off);
    }
    if (l == 0) {
        out[n * 2 + 0] = a0 / z + b2[0];
        out[n * 2 + 1] = a1 / z + b2[1];
    }
}

extern "C" void kernel_launch(void* const* d_in, const int* in_sizes, int n_in,
                              void* d_out, int out_size, void* d_ws, size_t ws_size,
                              hipStream_t stream)
{
    const float* x        = (const float*)d_in[0];
    const int*   ei       = (const int*)d_in[1];
    const float* W1       = (const float*)d_in[2];
    const float* att_src1 = (const float*)d_in[3];
    const float* att_dst1 = (const float*)d_in[4];
    const float* b1       = (const float*)d_in[5];
    const float* W2       = (const float*)d_in[6];
    const float* att_src2 = (const float*)d_in[7];
    const float* att_dst2 = (const float*)d_in[8];
    const float* b2       = (const float*)d_in[9];
    float* out = (float*)d_out;

    // --- workspace layout (all regions 16B aligned) ---
    int*    csr_src = (int*)d_ws;                            // NN*64*4 = 12.8 MB
    unsigned short* h1b = (unsigned short*)(csr_src + (size_t)NN * 64); // 25.6 MB
    unsigned short* Wt_bf = h1b + (size_t)NN * FH;           // 64 KB
    int*    pcnt  = (int*)(Wt_bf + FH * FIN);                // NN*32 = 6.4 MB
    int*    soff  = pcnt + (size_t)NN * R_REP;               // 6.4 MB
    int*    cnt   = soff + (size_t)NN * R_REP;               // 200 KB
    float*  a_s1  = (float*)(cnt + NN);                      // 800 KB
    float*  a_d1  = a_s1 + (size_t)NN * 4;                   // 800 KB
    float4* nd4   = (float4*)(a_d1 + (size_t)NN * 4);        // 800 KB

    k_count<<<CNT_WGS + PREP_WGS, 1024, 0, stream>>>(ei, W1, Wt_bf, pcnt);
    k_gx<<<OFF_NB + GEMM_NB, 256, 0, stream>>>(x, Wt_bf, att_src1, att_dst1,
                                               pcnt, soff, cnt, csr_src,
                                               h1b, a_s1, a_d1);
    k_scat2<<<CNT_WGS, 1024, 0, stream>>>(ei, soff, csr_src);
    k_agg1<<<(NN + 3) / 4, 256, 0, stream>>>(cnt, csr_src, a_s1, a_d1, h1b,
                                             b1, W2, att_src2, att_dst2, nd4);
    k_agg2<<<(NN + 15) / 16, 256, 0, stream>>>(cnt, csr_src, nd4, b2, out);
}